// Round 6
// baseline (231.150 us; speedup 1.0000x reference)
//
#include <hip/hip_runtime.h>

// PositionWiseSpatialAttention — fused flash-style kernel, MI355X gfx950.
//
// R11: V fragments direct-from-global; K stays LDS-staged.
// R10 post-mortem: removing the P LDS round-trip cut conflicts only 9.5M->8M
// and time was flat -> LDS *throughput* (not P conflicts) dominates: ~16
// ds_read_b128 + 4 ds_write_b128 per wave-tile ~= 50-57% of kernel cycles,
// while true MFMA-pipe busy ~9%. Half that LDS traffic is the V path, which
// after R10's permuted-V workspace is a pure copy-through (global -> LDS ->
// per-wave frags with IDENTICAL addresses). So V skips LDS: each wave b128-
// loads its 8 V frags from the permuted ws right after the staging barrier,
// ~400 cyc before PV needs them (K ds_reads + QK^T MFMAs + exp cover L2
// latency). NOT R8: K staging + both barriers remain (wave grouping), and
// only the copy-through path is bypassed. LDS ops/wave-tile 22 -> 10.
// launch_bounds(256,3): grid 768 = 3 blocks/CU caps occupancy at 12
// waves/CU anyway; bigger VGPR budget for the V frags, no spill.
// Math bit-identical to R10 (same split data, same contraction order).

#define NB    8
#define NT    12
#define NNODE 1024
#define ND    64
#define XROW  768   /* NT*ND: stride between consecutive n for fixed (b,t) */
#define NG    96    /* NB*NT */

typedef __bf16 bf16x8 __attribute__((ext_vector_type(8)));
typedef __bf16 bf16x4 __attribute__((ext_vector_type(4)));
typedef float  floatx4 __attribute__((ext_vector_type(4)));

#define MFMA(a,b,c) __builtin_amdgcn_mfma_f32_16x16x32_bf16((a),(b),(c),0,0,0)

#define QSCALE 0.18033688011112042f   /* 0.125 * log2(e) */

// LDS layout (bytes): K staging only + epilogue AG overlay.
#define KSTRIDE 72   /* bf16 per K row: 144 B */
#define AGSTRIDE 68  /* f32 per AG row (epilogue overlay) */
#define OFF_KHI 0
#define OFF_KLO 4608
#define SMEM6   (128 * AGSTRIDE * 4)      /* 34816 (>= 9216 staging) */
// fallback (R5) LDS map
#define VSTRIDE 40
#define PSTRIDE 36
#define OFF_VHI 9216
#define OFF_VLO 14336
#define OFF_P   19456
#define SMEM_FB (19456 + 128*PSTRIDE*4)   /* 37888 */

// workspace element offsets (__bf16 units)
#define WXHI  0          /* [96][1024][64] row-major hi          */
#define WXLO  6291456
#define WVPHI 12582912   /* [96][64][1024] transposed+PERMUTED hi */
#define WVPLO 18874368
#define WTHI  25165824   /* [64 o][64 d] theta^T hi               */
#define WTLO  25169920
#define WS_BYTES 50348032ULL

struct bfpair { __bf16 h, l; };

// error-compensated split: hi = RNE(f) via native fptrunc, lo = RNE(f - hi).
__device__ __forceinline__ bfpair split1(float f) {
    bfpair r;
    __bf16 hb = (__bf16)f;
    float hf = __builtin_bit_cast(float,
                   (unsigned)__builtin_bit_cast(unsigned short, hb) << 16);
    r.h = hb;
    r.l = (__bf16)(f - hf);
    return r;
}

// ---------------------------------------------------------------------------
// presplit: grid 1536 (96 g x 16 n-blocks), 256 threads. (R10, verified)
// Transposed split writes k-PERMUTED positions: position c in each 32-key
// tile holds key k(c) = ((c&7)>>2)*16 + (c>>3)*4 + (c&3).
// ---------------------------------------------------------------------------
__global__ void __launch_bounds__(256)
presplit(const float* __restrict__ x, const float* __restrict__ theta,
         __bf16* __restrict__ ws)
{
    __shared__ __align__(16) float T[64 * 68];
    const int tid  = threadIdx.x;
    const int bx   = blockIdx.x;
    const int g    = bx >> 4;
    const int nblk = bx & 15;
    const int bb   = g / NT;
    const int tt   = g - bb * NT;
    const int n0   = nblk * 64;

    __bf16* Xhi  = ws + WXHI  + (size_t)g * 65536;
    __bf16* Xlo  = ws + WXLO  + (size_t)g * 65536;
    __bf16* VPhi = ws + WVPHI + (size_t)g * 65536;
    __bf16* VPlo = ws + WVPLO + (size_t)g * 65536;
    const float* xg = x + (size_t)bb * (NNODE * XROW) + (size_t)tt * ND;

    #pragma unroll
    for (int i = 0; i < 4; ++i) {
        int chunk = i * 256 + tid;        // 0..1023
        int n  = chunk >> 4;              // 0..63
        int c4 = (chunk & 15) * 4;        // 0..60
        floatx4 f = *(const floatx4*)(xg + (size_t)(n0 + n) * XROW + c4);
        *(floatx4*)(T + n * 68 + c4) = f;
        bf16x4 h, l;
        #pragma unroll
        for (int j = 0; j < 4; ++j) {
            bfpair p = split1(f[j]); h[j] = p.h; l[j] = p.l;
        }
        *(bf16x4*)(Xhi + (size_t)(n0 + n) * 64 + c4) = h;
        *(bf16x4*)(Xlo + (size_t)(n0 + n) * 64 + c4) = l;
    }
    __syncthreads();

    {   // transposed + permuted split: thread owns (d, 16 consecutive dst pos)
        const int d  = tid >> 2;          // 0..63
        const int nc = (tid & 3) * 16;    // 0..48 (dst positions nc..nc+15)
        const int tb = nc & 32;           // 32-key tile base within the 64-blk
        bf16x8 h0, l0, h1, l1;
        #pragma unroll
        for (int j = 0; j < 8; ++j) {
            int c0 = (nc & 31) + j;       // dst position in tile
            int k0 = ((c0 & 7) >> 2) * 16 + (c0 >> 3) * 4 + (c0 & 3);
            bfpair p = split1(T[(tb + k0) * 68 + d]);
            h0[j] = p.h; l0[j] = p.l;
            int c1 = (nc & 31) + 8 + j;
            int k1 = ((c1 & 7) >> 2) * 16 + (c1 >> 3) * 4 + (c1 & 3);
            bfpair q = split1(T[(tb + k1) * 68 + d]);
            h1[j] = q.h; l1[j] = q.l;
        }
        __bf16* dsth = VPhi + (size_t)d * NNODE + n0 + nc;
        __bf16* dstl = VPlo + (size_t)d * NNODE + n0 + nc;
        *(bf16x8*)dsth = h0; *(bf16x8*)(dsth + 8) = h1;
        *(bf16x8*)dstl = l0; *(bf16x8*)(dstl + 8) = l1;
    }

    if (bx < 2) {                         // theta^T split (tiny)
        int c  = bx * 256 + tid;          // 0..511
        int o  = c >> 3;                  // 0..63
        int d0 = (c & 7) * 8;             // 0..56
        bf16x8 h, l;
        #pragma unroll
        for (int i = 0; i < 8; ++i) {
            bfpair p = split1(theta[(size_t)(d0 + i) * ND + o]);
            h[i] = p.h; l[i] = p.l;
        }
        *(bf16x8*)(ws + WTHI + (size_t)o * 64 + d0) = h;
        *(bf16x8*)(ws + WTLO + (size_t)o * 64 + d0) = l;
    }
}

// ---------------------------------------------------------------------------
// spattn6: grid 768 (bx = rblk*96 + g), 256 threads, 4 waves x 32 rows.
// Swapped QK^T; register P; K LDS-staged; V frags direct from permuted ws.
// ---------------------------------------------------------------------------
__global__ void __launch_bounds__(256, 3)
spattn6(const __bf16* __restrict__ ws, const float* __restrict__ adj,
        float* __restrict__ out)
{
    __shared__ __align__(16) char smem[SMEM6];
    __bf16* Khi = (__bf16*)(smem + OFF_KHI);
    __bf16* Klo = (__bf16*)(smem + OFF_KLO);

    const int tid  = threadIdx.x;
    const int wave = tid >> 6;          // 0..3, owns rows wave*32..+31
    const int lane = tid & 63;
    const int l16  = lane & 15;
    const int quad = lane >> 4;

    // bx = rblk*96 + g: all 8 row-blocks of a g share bx%8 -> same XCD.
    const int bx   = blockIdx.x;
    const int g    = bx % NG;           // 0..95
    const int rblk = bx / NG;           // 0..7
    const int bb   = g / NT;
    const int tt   = g - bb * NT;
    const int row0 = rblk * 128;

    const __bf16* xh  = ws + WXHI  + (size_t)g * 65536;
    const __bf16* xl  = ws + WXLO  + (size_t)g * 65536;
    const __bf16* vph = ws + WVPHI + (size_t)g * 65536;
    const __bf16* vpl = ws + WVPLO + (size_t)g * 65536;

    // ---- Q fragments b128 from row-major split arrays (B operand) ----
    bf16x8 qhi[2][2], qlo[2][2];
    #pragma unroll
    for (int mt = 0; mt < 2; ++mt) {
        const __bf16* q0 = xh + (size_t)(row0 + wave*32 + mt*16 + l16) * 64 + quad*8;
        const __bf16* q1 = xl + (size_t)(row0 + wave*32 + mt*16 + l16) * 64 + quad*8;
        #pragma unroll
        for (int ks = 0; ks < 2; ++ks) {
            qhi[mt][ks] = *(const bf16x8*)(q0 + ks*32);
            qlo[mt][ks] = *(const bf16x8*)(q1 + ks*32);
        }
    }

    const floatx4 vzero = {0.f, 0.f, 0.f, 0.f};
    floatx4 acc[2][4];
    #pragma unroll
    for (int mt = 0; mt < 2; ++mt)
        #pragma unroll
        for (int dt = 0; dt < 4; ++dt)
            acc[mt][dt] = vzero;
    float lpart[2] = {0.f, 0.f};        // per-lane partial: q = l16 (per mt)

    // K staging map (R9/R10 geometry)
    const int skey = tid >> 3;          // 0..31
    const int sd0  = (tid & 7) * 8;     // 0..56

    bf16x8 kh, kl;                      // register prefetch (tile 0)
    kh = *(const bf16x8*)(xh + (size_t)skey * 64 + sd0);
    kl = *(const bf16x8*)(xl + (size_t)skey * 64 + sd0);

    for (int ct = 0; ct < 32; ++ct) {
        const int key0 = ct * 32;
        __syncthreads();                       // prior tile's K LDS reads done
        *(bf16x8*)(Khi + skey*KSTRIDE + sd0) = kh;
        *(bf16x8*)(Klo + skey*KSTRIDE + sd0) = kl;
        __syncthreads();                       // staging visible
        if (ct < 31) { // register prefetch of next K tile, overlaps compute
            const int nk = key0 + 32;
            kh = *(const bf16x8*)(xh + (size_t)(nk + skey) * 64 + sd0);
            kl = *(const bf16x8*)(xl + (size_t)(nk + skey) * 64 + sd0);
        }
        // V frags for THIS tile, direct from permuted ws (addresses equal
        // what R10's staging copied; consumed after QK+exp -> L2 latency
        // fully covered). Wave-independent data -> L1-hot for 3 of 4 waves.
        bf16x8 vvh[4], vvl[4];
        #pragma unroll
        for (int dt = 0; dt < 4; ++dt) {
            vvh[dt] = *(const bf16x8*)(vph + (size_t)(dt*16 + l16) * NNODE + key0 + quad*8);
            vvl[dt] = *(const bf16x8*)(vpl + (size_t)(dt*16 + l16) * NNODE + key0 + quad*8);
        }
        // adj: float4 loads; lane l16 = q-row, quad*4+r = key within nt-tile
        floatx4 av[2][2];
        #pragma unroll
        for (int mt = 0; mt < 2; ++mt)
            #pragma unroll
            for (int nt = 0; nt < 2; ++nt)
                av[mt][nt] = *(const floatx4*)(adj
                    + (size_t)(row0 + wave*32 + mt*16 + l16) * NNODE
                    + key0 + nt*16 + quad*4);

        // ---- S^T = K Q^T (swapped operands; 3-term split bf16) ----
        // Output: col = q = l16, row = key = nt*16 + quad*4 + r.
        floatx4 S[2][2] = {{vzero, vzero}, {vzero, vzero}};   // [mt][nt]
        #pragma unroll
        for (int ks = 0; ks < 2; ++ks) {
            #pragma unroll
            for (int nt = 0; nt < 2; ++nt) {
                bf16x8 ah = *(const bf16x8*)(Khi + (nt*16 + l16)*KSTRIDE + ks*32 + quad*8);
                bf16x8 al = *(const bf16x8*)(Klo + (nt*16 + l16)*KSTRIDE + ks*32 + quad*8);
                #pragma unroll
                for (int mt = 0; mt < 2; ++mt) {
                    S[mt][nt] = MFMA(ah, qhi[mt][ks], S[mt][nt]);
                    S[mt][nt] = MFMA(ah, qlo[mt][ks], S[mt][nt]);
                    S[mt][nt] = MFMA(al, qhi[mt][ks], S[mt][nt]);
                }
            }
        }

        // ---- exp2 + adj-mask + split, ALL in registers ----
        bf16x8 pah[2], pal[2];
        #pragma unroll
        for (int mt = 0; mt < 2; ++mt)
            #pragma unroll
            for (int nt = 0; nt < 2; ++nt)
                #pragma unroll
                for (int r = 0; r < 4; ++r) {
                    float w = __builtin_amdgcn_exp2f(S[mt][nt][r] * QSCALE);
                    lpart[mt] += w;
                    bfpair pp = split1(av[mt][nt][r] * w);
                    pah[mt][nt*4 + r] = pp.h;
                    pal[mt][nt*4 + r] = pp.l;
                }

        // ---- agg += P . V (3-term split; V B-frags in registers) ----
        #pragma unroll
        for (int dt = 0; dt < 4; ++dt) {
            #pragma unroll
            for (int mt = 0; mt < 2; ++mt) {
                acc[mt][dt] = MFMA(pah[mt], vvh[dt], acc[mt][dt]);
                acc[mt][dt] = MFMA(pal[mt], vvh[dt], acc[mt][dt]);
                acc[mt][dt] = MFMA(pah[mt], vvl[dt], acc[mt][dt]);
            }
        }
    }

    // ---- denominator: reduce across quads (each lane has q = l16) ----
    float linv[2][4];
    #pragma unroll
    for (int mt = 0; mt < 2; ++mt) {
        float lv = lpart[mt];
        lv += __shfl_xor(lv, 16);
        lv += __shfl_xor(lv, 32);           // lanes 0..15 hold full sums
        #pragma unroll
        for (int r = 0; r < 4; ++r)
            linv[mt][r] = 1.0f / __shfl(lv, quad*4 + r);
    }

    // ---- epilogue: out = relu((agg/l) @ theta), split-bf16 MFMA ----
    __syncthreads();                       // everyone done with K LDS
    float* AG = (float*)smem;              // [128][AGSTRIDE] overlay
    #pragma unroll
    for (int mt = 0; mt < 2; ++mt)
        #pragma unroll
        for (int dt = 0; dt < 4; ++dt)
            #pragma unroll
            for (int r = 0; r < 4; ++r)
                AG[(wave*32 + mt*16 + quad*4 + r)*AGSTRIDE + dt*16 + l16]
                    = acc[mt][dt][r] * linv[mt][r];

    const __bf16* Th = ws + WTHI;
    const __bf16* Tl = ws + WTLO;
    bf16x8 th[4][2], tlw[4][2];
    #pragma unroll
    for (int ot = 0; ot < 4; ++ot)
        #pragma unroll
        for (int ks = 0; ks < 2; ++ks) {
            th[ot][ks]  = *(const bf16x8*)(Th + (size_t)(ot*16 + l16)*64 + ks*32 + quad*8);
            tlw[ot][ks] = *(const bf16x8*)(Tl + (size_t)(ot*16 + l16)*64 + ks*32 + quad*8);
        }

    floatx4 oacc[2][4];
    #pragma unroll
    for (int mt = 0; mt < 2; ++mt)
        #pragma unroll
        for (int ot = 0; ot < 4; ++ot)
            oacc[mt][ot] = vzero;
    __syncthreads();                       // AG region fully written
    #pragma unroll
    for (int ks = 0; ks < 2; ++ks) {
        bf16x8 ah[2], al[2];
        #pragma unroll
        for (int mt = 0; mt < 2; ++mt) {
            const float* ap = AG + (wave*32 + mt*16 + l16)*AGSTRIDE + ks*32 + quad*8;
            floatx4 a0 = *(const floatx4*)ap;
            floatx4 a1 = *(const floatx4*)(ap + 4);
            #pragma unroll
            for (int i = 0; i < 4; ++i) {
                bfpair q0 = split1(a0[i]); ah[mt][i]   = q0.h; al[mt][i]   = q0.l;
                bfpair q1 = split1(a1[i]); ah[mt][4+i] = q1.h; al[mt][4+i] = q1.l;
            }
        }
        #pragma unroll
        for (int ot = 0; ot < 4; ++ot)
            #pragma unroll
            for (int mt = 0; mt < 2; ++mt) {
                oacc[mt][ot] = MFMA(ah[mt], th[ot][ks], oacc[mt][ot]);
                oacc[mt][ot] = MFMA(al[mt], th[ot][ks], oacc[mt][ot]);
                oacc[mt][ot] = MFMA(ah[mt], tlw[ot][ks], oacc[mt][ot]);
            }
    }

    float* obase = out + (size_t)bb * (NNODE * XROW) + tt * ND;
    #pragma unroll
    for (int mt = 0; mt < 2; ++mt)
        #pragma unroll
        for (int ot = 0; ot < 4; ++ot)
            #pragma unroll
            for (int r = 0; r < 4; ++r) {
                float v = oacc[mt][ot][r];
                obase[(size_t)(row0 + wave*32 + mt*16 + quad*4 + r) * XROW + ot*16 + l16]
                    = v > 0.f ? v : 0.f;
            }
}

// ---------------------------------------------------------------------------
// Fallback: verified R5 kernel (used only if workspace is too small).
// ---------------------------------------------------------------------------
__global__ void __launch_bounds__(256, 2)
spattn_fb(const float* __restrict__ x, const float* __restrict__ adj,
          const float* __restrict__ theta, float* __restrict__ out)
{
    __shared__ __align__(16) char smem[SMEM_FB];
    __bf16* Khi = (__bf16*)(smem + OFF_KHI);
    __bf16* Klo = (__bf16*)(smem + OFF_KLO);
    __bf16* Vhi = (__bf16*)(smem + OFF_VHI);
    __bf16* Vlo = (__bf16*)(smem + OFF_VLO);
    float*  Pm  = (float*)(smem + OFF_P);

    const int tid  = threadIdx.x;
    const int wave = tid >> 6;
    const int lane = tid & 63;
    const int l16  = lane & 15;
    const int quad = lane >> 4;

    const int bx   = blockIdx.x;
    const int g    = bx >> 3;
    const int rblk = bx & 7;
    const int bb   = g / NT;
    const int tt   = g - bb * NT;
    const int row0 = rblk * 128;

    const float* xbase = x + (size_t)bb * (NNODE * XROW) + tt * ND;

    bf16x8 qhi[2][2], qlo[2][2];
    #pragma unroll
    for (int mt = 0; mt < 2; ++mt) {
        const float* qsrc = xbase + (size_t)(row0 + wave*32 + mt*16 + l16) * XROW;
        #pragma unroll
        for (int ks = 0; ks < 2; ++ks) {
            floatx4 f0 = *(const floatx4*)(qsrc + ks*32 + quad*8);
            floatx4 f1 = *(const floatx4*)(qsrc + ks*32 + quad*8 + 4);
            #pragma unroll
            for (int i = 0; i < 4; ++i) {
                bfpair p0 = split1(f0[i]*QSCALE);
                qhi[mt][ks][i]   = p0.h; qlo[mt][ks][i]   = p0.l;
                bfpair p1 = split1(f1[i]*QSCALE);
                qhi[mt][ks][4+i] = p1.h; qlo[mt][ks][4+i] = p1.l;
            }
        }
    }

    const floatx4 vzero = {0.f, 0.f, 0.f, 0.f};
    floatx4 acc[2][4];
    #pragma unroll
    for (int mt = 0; mt < 2; ++mt)
        #pragma unroll
        for (int dt = 0; dt < 4; ++dt)
            acc[mt][dt] = vzero;
    float lpart[2][4] = {{0.f,0.f,0.f,0.f},{0.f,0.f,0.f,0.f}};

    const int skey = tid >> 3;
    const int sd0  = (tid & 7) * 8;
    const int svd  = tid >> 2;
    const int svk0 = (tid & 3) * 8;
    floatx4 kf0, kf1;
    float vf[8];

    {
        const float* ksrc = xbase + (size_t)skey * XROW + sd0;
        kf0 = *(const floatx4*)ksrc;
        kf1 = *(const floatx4*)(ksrc + 4);
        const float* vsrc = xbase + (size_t)svk0 * XROW + svd;
        #pragma unroll
        for (int i = 0; i < 8; ++i) vf[i] = vsrc[i * XROW];
    }

    for (int ct = 0; ct < 32; ++ct) {
        const int key0 = ct * 32;
        __syncthreads();
        {
            bf16x8 h, l;
            #pragma unroll
            for (int i = 0; i < 4; ++i) {
                bfpair p0 = split1(kf0[i]); h[i]   = p0.h; l[i]   = p0.l;
                bfpair p1 = split1(kf1[i]); h[4+i] = p1.h; l[4+i] = p1.l;
            }
            *(bf16x8*)(Khi + skey*KSTRIDE + sd0) = h;
            *(bf16x8*)(Klo + skey*KSTRIDE + sd0) = l;
            bf16x8 vh, vl;
            #pragma unroll
            for (int i = 0; i < 8; ++i) {
                bfpair p = split1(vf[i]); vh[i] = p.h; vl[i] = p.l;
            }
            *(bf16x8*)(Vhi + svd*VSTRIDE + svk0) = vh;
            *(bf16x8*)(Vlo + svd*VSTRIDE + svk0) = vl;
        }
        __syncthreads();
        if (ct < 31) {
            const int nk = key0 + 32;
            const float* ksrc = xbase + (size_t)(nk + skey) * XROW + sd0;
            kf0 = *(const floatx4*)ksrc;
            kf1 = *(const floatx4*)(ksrc + 4);
            const float* vsrc = xbase + (size_t)(nk + svk0) * XROW + svd;
            #pragma unroll
            for (int i = 0; i < 8; ++i) vf[i] = vsrc[i * XROW];
        }
        float av[2][2][4];
        #pragma unroll
        for (int mt = 0; mt < 2; ++mt)
            #pragma unroll
            for (int nt = 0; nt < 2; ++nt)
                #pragma unroll
                for (int r = 0; r < 4; ++r)
                    av[mt][nt][r] = adj[(size_t)(row0 + wave*32 + mt*16 + quad*4 + r) * NNODE
                                        + key0 + nt*16 + l16];

        floatx4 S[2][2] = {{vzero, vzero}, {vzero, vzero}};
        #pragma unroll
        for (int ks = 0; ks < 2; ++ks) {
            #pragma unroll
            for (int nt = 0; nt < 2; ++nt) {
                bf16x8 bh = *(const bf16x8*)(Khi + (nt*16 + l16)*KSTRIDE + ks*32 + quad*8);
                bf16x8 bl = *(const bf16x8*)(Klo + (nt*16 + l16)*KSTRIDE + ks*32 + quad*8);
                #pragma unroll
                for (int mt = 0; mt < 2; ++mt) {
                    S[mt][nt] = MFMA(qhi[mt][ks], bh, S[mt][nt]);
                    S[mt][nt] = MFMA(qlo[mt][ks], bh, S[mt][nt]);
                    S[mt][nt] = MFMA(qhi[mt][ks], bl, S[mt][nt]);
                }
            }
        }
        #pragma unroll
        for (int mt = 0; mt < 2; ++mt)
            #pragma unroll
            for (int nt = 0; nt < 2; ++nt)
                #pragma unroll
                for (int r = 0; r < 4; ++r) {
                    float w = __builtin_amdgcn_exp2f(S[mt][nt][r]);
                    lpart[mt][r] += w;
                    Pm[(wave*32 + mt*16 + quad*4 + r)*PSTRIDE + nt*16 + l16] = av[mt][nt][r] * w;
                }
        bf16x8 pah[2], pal[2];
        #pragma unroll
        for (int mt = 0; mt < 2; ++mt) {
            const float* pp = Pm + (wave*32 + mt*16 + l16)*PSTRIDE + quad*8;
            floatx4 p0 = *(const floatx4*)pp;
            floatx4 p1 = *(const floatx4*)(pp + 4);
            #pragma unroll
            for (int i = 0; i < 4; ++i) {
                bfpair q0 = split1(p0[i]); pah[mt][i]   = q0.h; pal[mt][i]   = q0.l;
                bfpair q1 = split1(p1[i]); pah[mt][4+i] = q1.h; pal[mt][4+i] = q1.l;
            }
        }
        #pragma unroll
        for (int dt = 0; dt < 4; ++dt) {
            bf16x8 vh = *(const bf16x8*)(Vhi + (dt*16 + l16)*VSTRIDE + quad*8);
            bf16x8 vl = *(const bf16x8*)(Vlo + (dt*16 + l16)*VSTRIDE + quad*8);
            #pragma unroll
            for (int mt = 0; mt < 2; ++mt) {
                acc[mt][dt] = MFMA(pah[mt], vh, acc[mt][dt]);
                acc[mt][dt] = MFMA(pal[mt], vh, acc[mt][dt]);
                acc[mt][dt] = MFMA(pah[mt], vl, acc[mt][dt]);
            }
        }
    }

    float linv[2][4];
    #pragma unroll
    for (int mt = 0; mt < 2; ++mt)
        #pragma unroll
        for (int r = 0; r < 4; ++r) {
            float lv = lpart[mt][r];
            lv += __shfl_xor(lv, 1);
            lv += __shfl_xor(lv, 2);
            lv += __shfl_xor(lv, 4);
            lv += __shfl_xor(lv, 8);
            linv[mt][r] = 1.0f / lv;
        }

    __syncthreads();
    float* AG = (float*)smem;
    #pragma unroll
    for (int mt = 0; mt < 2; ++mt)
        #pragma unroll
        for (int dt = 0; dt < 4; ++dt)
            #pragma unroll
            for (int r = 0; r < 4; ++r)
                AG[(wave*32 + mt*16 + quad*4 + r)*AGSTRIDE + dt*16 + l16]
                    = acc[mt][dt][r] * linv[mt][r];

    bf16x8 th[4][2], tl[4][2];
    #pragma unroll
    for (int ot = 0; ot < 4; ++ot)
        #pragma unroll
        for (int ks = 0; ks < 2; ++ks)
            #pragma unroll
            for (int j = 0; j < 8; ++j) {
                float tv = theta[(ks*32 + quad*8 + j)*ND + ot*16 + l16];
                bfpair p = split1(tv);
                th[ot][ks][j] = p.h; tl[ot][ks][j] = p.l;
            }

    floatx4 oacc[2][4];
    #pragma unroll
    for (int mt = 0; mt < 2; ++mt)
        #pragma unroll
        for (int ot = 0; ot < 4; ++ot)
            oacc[mt][ot] = vzero;
    __syncthreads();
    #pragma unroll
    for (int ks = 0; ks < 2; ++ks) {
        bf16x8 ah[2], al[2];
        #pragma unroll
        for (int mt = 0; mt < 2; ++mt) {
            const float* ap = AG + (wave*32 + mt*16 + l16)*AGSTRIDE + ks*32 + quad*8;
            floatx4 a0 = *(const floatx4*)ap;
            floatx4 a1 = *(const floatx4*)(ap + 4);
            #pragma unroll
            for (int i = 0; i < 4; ++i) {
                bfpair q0 = split1(a0[i]); ah[mt][i]   = q0.h; al[mt][i]   = q0.l;
                bfpair q1 = split1(a1[i]); ah[mt][4+i] = q1.h; al[mt][4+i] = q1.l;
            }
        }
        #pragma unroll
        for (int ot = 0; ot < 4; ++ot)
            #pragma unroll
            for (int mt = 0; mt < 2; ++mt) {
                oacc[mt][ot] = MFMA(ah[mt], th[ot][ks], oacc[mt][ot]);
                oacc[mt][ot] = MFMA(al[mt], th[ot][ks], oacc[mt][ot]);
                oacc[mt][ot] = MFMA(ah[mt], tl[ot][ks], oacc[mt][ot]);
            }
    }

    float* obase = out + (size_t)bb * (NNODE * XROW) + tt * ND;
    #pragma unroll
    for (int mt = 0; mt < 2; ++mt)
        #pragma unroll
        for (int ot = 0; ot < 4; ++ot)
            #pragma unroll
            for (int r = 0; r < 4; ++r) {
                float v = oacc[mt][ot][r];
                obase[(size_t)(row0 + wave*32 + mt*16 + quad*4 + r) * XROW + ot*16 + l16]
                    = v > 0.f ? v : 0.f;
            }
}

extern "C" void kernel_launch(void* const* d_in, const int* in_sizes, int n_in,
                              void* d_out, int out_size, void* d_ws, size_t ws_size,
                              hipStream_t stream) {
    (void)in_sizes; (void)n_in; (void)out_size;
    const float* x     = (const float*)d_in[0];
    const float* adj   = (const float*)d_in[1];
    const float* theta = (const float*)d_in[2];
    float* out = (float*)d_out;
    if (d_ws != nullptr && ws_size >= WS_BYTES) {
        __bf16* ws = (__bf16*)d_ws;
        presplit<<<dim3(1536), dim3(256), 0, stream>>>(x, theta, ws);
        spattn6<<<dim3(768), dim3(256), 0, stream>>>(ws, adj, out);
    } else {
        spattn_fb<<<dim3(768), dim3(256), 0, stream>>>(x, adj, theta, out);
    }
}

// Round 7
// 183.967 us; speedup vs baseline: 1.2565x; 1.2565x over previous
//
#include <hip/hip_runtime.h>

// PositionWiseSpatialAttention — fused flash-style kernel, MI355X gfx950.
//
// R12: occupancy push with the verified R10 engine.
// Ledger: R10 (register-P) flat vs R9, R11/R8 (LDS bypass) regress -> kernel
// is LATENCY-bound at 3 waves/SIMD (grid 768 x 4-wave blocks = 12 waves/CU;
// VGPR 64 / LDS 34.8KB would allow 32 waves). Fix the grid, not the math:
// 64-row blocks, 4 waves x 16 rows, grid 1536. LDS = 19456 B -> 8 blocks/CU
// fit; mt-dimension gone -> per-wave state ~halves (spattn5 was 64 VGPR with
// 2x state) -> launch_bounds(256,6) (85-reg budget, wide margin vs est. ~55;
// R6's spill disaster was a 40-reg budget). Expected 6-8 waves/SIMD and
// halved per-wave dependency chains (lpart chain 16->8 adds, 24->12 MFMA
// bursts). Costs accepted because those pipes are ~30% busy: LDS frag reads
// duplicate over 2x waves, K/V panels staged by 16 blocks/g (L2-hot).
// R7's 64-row loss came from its 22-LDS-op structure + g-major XCD map,
// both fixed here (10 LDS ops/wave-tile; rblk-major bx keeps a g's 16
// row-blocks on one XCD). Math identical to R10 (same split data, same
// permuted-V contraction order).

#define NB    8
#define NT    12
#define NNODE 1024
#define ND    64
#define XROW  768   /* NT*ND: stride between consecutive n for fixed (b,t) */
#define NG    96    /* NB*NT */

typedef __bf16 bf16x8 __attribute__((ext_vector_type(8)));
typedef __bf16 bf16x4 __attribute__((ext_vector_type(4)));
typedef float  floatx4 __attribute__((ext_vector_type(4)));

#define MFMA(a,b,c) __builtin_amdgcn_mfma_f32_16x16x32_bf16((a),(b),(c),0,0,0)

#define QSCALE 0.18033688011112042f   /* 0.125 * log2(e) */

// LDS layout (bytes); K/V staging + epilogue AG overlay (64 rows).
#define KSTRIDE 72   /* bf16 per K row: 144 B */
#define VSTRIDE 40   /* bf16 per V row:  80 B */
#define AGSTRIDE 68  /* f32 per AG row (epilogue overlay, 64x68x4=17408) */
#define OFF_KHI 0
#define OFF_KLO 4608
#define OFF_VHI 9216
#define OFF_VLO 14336
#define SMEM7   19456                     /* 8 blocks/CU: 8*19456 = 155.6KB */
// fallback (R5) LDS map
#define PSTRIDE 36
#define OFF_P   19456
#define SMEM_FB (19456 + 128*PSTRIDE*4)   /* 37888 */

// workspace element offsets (__bf16 units)
#define WXHI  0          /* [96][1024][64] row-major hi          */
#define WXLO  6291456
#define WVPHI 12582912   /* [96][64][1024] transposed+PERMUTED hi */
#define WVPLO 18874368
#define WTHI  25165824   /* [64 o][64 d] theta^T hi               */
#define WTLO  25169920
#define WS_BYTES 50348032ULL

struct bfpair { __bf16 h, l; };

// error-compensated split: hi = RNE(f) via native fptrunc, lo = RNE(f - hi).
__device__ __forceinline__ bfpair split1(float f) {
    bfpair r;
    __bf16 hb = (__bf16)f;
    float hf = __builtin_bit_cast(float,
                   (unsigned)__builtin_bit_cast(unsigned short, hb) << 16);
    r.h = hb;
    r.l = (__bf16)(f - hf);
    return r;
}

// ---------------------------------------------------------------------------
// presplit: grid 1536 (96 g x 16 n-blocks), 256 threads. (R10, verified)
// Transposed split writes k-PERMUTED positions: position c in each 32-key
// tile holds key k(c) = ((c&7)>>2)*16 + (c>>3)*4 + (c&3).
// ---------------------------------------------------------------------------
__global__ void __launch_bounds__(256)
presplit(const float* __restrict__ x, const float* __restrict__ theta,
         __bf16* __restrict__ ws)
{
    __shared__ __align__(16) float T[64 * 68];
    const int tid  = threadIdx.x;
    const int bx   = blockIdx.x;
    const int g    = bx >> 4;
    const int nblk = bx & 15;
    const int bb   = g / NT;
    const int tt   = g - bb * NT;
    const int n0   = nblk * 64;

    __bf16* Xhi  = ws + WXHI  + (size_t)g * 65536;
    __bf16* Xlo  = ws + WXLO  + (size_t)g * 65536;
    __bf16* VPhi = ws + WVPHI + (size_t)g * 65536;
    __bf16* VPlo = ws + WVPLO + (size_t)g * 65536;
    const float* xg = x + (size_t)bb * (NNODE * XROW) + (size_t)tt * ND;

    #pragma unroll
    for (int i = 0; i < 4; ++i) {
        int chunk = i * 256 + tid;        // 0..1023
        int n  = chunk >> 4;              // 0..63
        int c4 = (chunk & 15) * 4;        // 0..60
        floatx4 f = *(const floatx4*)(xg + (size_t)(n0 + n) * XROW + c4);
        *(floatx4*)(T + n * 68 + c4) = f;
        bf16x4 h, l;
        #pragma unroll
        for (int j = 0; j < 4; ++j) {
            bfpair p = split1(f[j]); h[j] = p.h; l[j] = p.l;
        }
        *(bf16x4*)(Xhi + (size_t)(n0 + n) * 64 + c4) = h;
        *(bf16x4*)(Xlo + (size_t)(n0 + n) * 64 + c4) = l;
    }
    __syncthreads();

    {   // transposed + permuted split: thread owns (d, 16 consecutive dst pos)
        const int d  = tid >> 2;          // 0..63
        const int nc = (tid & 3) * 16;    // 0..48 (dst positions nc..nc+15)
        const int tb = nc & 32;           // 32-key tile base within the 64-blk
        bf16x8 h0, l0, h1, l1;
        #pragma unroll
        for (int j = 0; j < 8; ++j) {
            int c0 = (nc & 31) + j;       // dst position in tile
            int k0 = ((c0 & 7) >> 2) * 16 + (c0 >> 3) * 4 + (c0 & 3);
            bfpair p = split1(T[(tb + k0) * 68 + d]);
            h0[j] = p.h; l0[j] = p.l;
            int c1 = (nc & 31) + 8 + j;
            int k1 = ((c1 & 7) >> 2) * 16 + (c1 >> 3) * 4 + (c1 & 3);
            bfpair q = split1(T[(tb + k1) * 68 + d]);
            h1[j] = q.h; l1[j] = q.l;
        }
        __bf16* dsth = VPhi + (size_t)d * NNODE + n0 + nc;
        __bf16* dstl = VPlo + (size_t)d * NNODE + n0 + nc;
        *(bf16x8*)dsth = h0; *(bf16x8*)(dsth + 8) = h1;
        *(bf16x8*)dstl = l0; *(bf16x8*)(dstl + 8) = l1;
    }

    if (bx < 2) {                         // theta^T split (tiny)
        int c  = bx * 256 + tid;          // 0..511
        int o  = c >> 3;                  // 0..63
        int d0 = (c & 7) * 8;             // 0..56
        bf16x8 h, l;
        #pragma unroll
        for (int i = 0; i < 8; ++i) {
            bfpair p = split1(theta[(size_t)(d0 + i) * ND + o]);
            h[i] = p.h; l[i] = p.l;
        }
        *(bf16x8*)(ws + WTHI + (size_t)o * 64 + d0) = h;
        *(bf16x8*)(ws + WTLO + (size_t)o * 64 + d0) = l;
    }
}

// ---------------------------------------------------------------------------
// spattn7: grid 1536 (bx = rblk*96 + g), 256 threads, 4 waves x 16 rows.
// R10 engine (swapped QK^T, register P, K+V LDS staging) at 64-row blocks.
// ---------------------------------------------------------------------------
__global__ void __launch_bounds__(256, 6)
spattn7(const __bf16* __restrict__ ws, const float* __restrict__ adj,
        float* __restrict__ out)
{
    __shared__ __align__(16) char smem[SMEM7];
    __bf16* Khi = (__bf16*)(smem + OFF_KHI);
    __bf16* Klo = (__bf16*)(smem + OFF_KLO);
    __bf16* Vhi = (__bf16*)(smem + OFF_VHI);
    __bf16* Vlo = (__bf16*)(smem + OFF_VLO);

    const int tid  = threadIdx.x;
    const int wave = tid >> 6;          // 0..3, owns rows wave*16..+15
    const int lane = tid & 63;
    const int l16  = lane & 15;
    const int quad = lane >> 4;

    // bx = rblk*96 + g: all 16 row-blocks of a g share bx%8 -> same XCD.
    const int bx   = blockIdx.x;
    const int g    = bx % NG;           // 0..95
    const int rblk = bx / NG;           // 0..15
    const int bb   = g / NT;
    const int tt   = g - bb * NT;
    const int row0 = rblk * 64;

    const __bf16* xh  = ws + WXHI  + (size_t)g * 65536;
    const __bf16* xl  = ws + WXLO  + (size_t)g * 65536;
    const __bf16* vph = ws + WVPHI + (size_t)g * 65536;
    const __bf16* vpl = ws + WVPLO + (size_t)g * 65536;

    // ---- Q fragments b128 from row-major split arrays (B operand) ----
    bf16x8 qhi[2], qlo[2];
    {
        const __bf16* q0 = xh + (size_t)(row0 + wave*16 + l16) * 64 + quad*8;
        const __bf16* q1 = xl + (size_t)(row0 + wave*16 + l16) * 64 + quad*8;
        #pragma unroll
        for (int ks = 0; ks < 2; ++ks) {
            qhi[ks] = *(const bf16x8*)(q0 + ks*32);
            qlo[ks] = *(const bf16x8*)(q1 + ks*32);
        }
    }

    const floatx4 vzero = {0.f, 0.f, 0.f, 0.f};
    floatx4 acc[4];
    #pragma unroll
    for (int dt = 0; dt < 4; ++dt) acc[dt] = vzero;
    float lpart = 0.f;                  // per-lane partial for q = l16

    // staging maps (R10 geometry, verified)
    const int skey = tid >> 3;          // 0..31
    const int sd0  = (tid & 7) * 8;     // 0..56
    const int svd  = tid >> 2;          // 0..63
    const int svk0 = (tid & 3) * 8;     // 0..24

    bf16x8 kh, kl, vhs, vls;            // register prefetch (tile 0)
    kh  = *(const bf16x8*)(xh  + (size_t)skey * 64 + sd0);
    kl  = *(const bf16x8*)(xl  + (size_t)skey * 64 + sd0);
    vhs = *(const bf16x8*)(vph + (size_t)svd * NNODE + svk0);
    vls = *(const bf16x8*)(vpl + (size_t)svd * NNODE + svk0);

    for (int ct = 0; ct < 32; ++ct) {
        const int key0 = ct * 32;
        __syncthreads();                       // prior tile's LDS reads done
        *(bf16x8*)(Khi + skey*KSTRIDE + sd0) = kh;
        *(bf16x8*)(Klo + skey*KSTRIDE + sd0) = kl;
        *(bf16x8*)(Vhi + svd*VSTRIDE + svk0) = vhs;
        *(bf16x8*)(Vlo + svd*VSTRIDE + svk0) = vls;
        __syncthreads();                       // staging visible
        if (ct < 31) { // register prefetch of next tile, overlaps compute
            const int nk = key0 + 32;
            kh  = *(const bf16x8*)(xh  + (size_t)(nk + skey) * 64 + sd0);
            kl  = *(const bf16x8*)(xl  + (size_t)(nk + skey) * 64 + sd0);
            vhs = *(const bf16x8*)(vph + (size_t)svd * NNODE + nk + svk0);
            vls = *(const bf16x8*)(vpl + (size_t)svd * NNODE + nk + svk0);
        }
        // adj: float4 loads; lane l16 = q-row, quad*4+r = key within nt-tile
        floatx4 av[2];
        #pragma unroll
        for (int nt = 0; nt < 2; ++nt)
            av[nt] = *(const floatx4*)(adj
                + (size_t)(row0 + wave*16 + l16) * NNODE
                + key0 + nt*16 + quad*4);

        // ---- S^T = K Q^T (swapped operands; 3-term split bf16) ----
        // Output: col = q = l16, row = key = nt*16 + quad*4 + r.
        floatx4 S[2] = {vzero, vzero};
        #pragma unroll
        for (int ks = 0; ks < 2; ++ks) {
            #pragma unroll
            for (int nt = 0; nt < 2; ++nt) {
                bf16x8 ah = *(const bf16x8*)(Khi + (nt*16 + l16)*KSTRIDE + ks*32 + quad*8);
                bf16x8 al = *(const bf16x8*)(Klo + (nt*16 + l16)*KSTRIDE + ks*32 + quad*8);
                S[nt] = MFMA(ah, qhi[ks], S[nt]);
                S[nt] = MFMA(ah, qlo[ks], S[nt]);
                S[nt] = MFMA(al, qhi[ks], S[nt]);
            }
        }

        // ---- exp2 + adj-mask + split, ALL in registers ----
        bf16x8 pah, pal;
        #pragma unroll
        for (int nt = 0; nt < 2; ++nt)
            #pragma unroll
            for (int r = 0; r < 4; ++r) {
                float w = __builtin_amdgcn_exp2f(S[nt][r] * QSCALE);
                lpart += w;
                bfpair pp = split1(av[nt][r] * w);
                pah[nt*4 + r] = pp.h;
                pal[nt*4 + r] = pp.l;
            }

        // ---- agg += P . V (3-term split; V B-frags from permuted LDS) ----
        #pragma unroll
        for (int dt = 0; dt < 4; ++dt) {
            bf16x8 vvh = *(const bf16x8*)(Vhi + (dt*16 + l16)*VSTRIDE + quad*8);
            bf16x8 vvl = *(const bf16x8*)(Vlo + (dt*16 + l16)*VSTRIDE + quad*8);
            acc[dt] = MFMA(pah, vvh, acc[dt]);
            acc[dt] = MFMA(pal, vvh, acc[dt]);
            acc[dt] = MFMA(pah, vvl, acc[dt]);
        }
    }

    // ---- denominator: reduce across quads (each lane has q = l16) ----
    float linv[4];
    {
        float lv = lpart;
        lv += __shfl_xor(lv, 16);
        lv += __shfl_xor(lv, 32);           // all lanes hold full sum for q=l16
        #pragma unroll
        for (int r = 0; r < 4; ++r)
            linv[r] = 1.0f / __shfl(lv, quad*4 + r);
    }

    // ---- epilogue: out = relu((agg/l) @ theta), split-bf16 MFMA ----
    __syncthreads();                       // everyone done with K/V LDS
    float* AG = (float*)smem;              // [64][AGSTRIDE] overlay
    #pragma unroll
    for (int dt = 0; dt < 4; ++dt)
        #pragma unroll
        for (int r = 0; r < 4; ++r)
            AG[(wave*16 + quad*4 + r)*AGSTRIDE + dt*16 + l16]
                = acc[dt][r] * linv[r];
    __syncthreads();                       // AG region fully written

    const __bf16* Th = ws + WTHI;
    const __bf16* Tl = ws + WTLO;
    floatx4 oacc[4];
    #pragma unroll
    for (int ot = 0; ot < 4; ++ot) oacc[ot] = vzero;

    #pragma unroll
    for (int ks = 0; ks < 2; ++ks) {
        bf16x8 ah, al;
        {
            const float* ap = AG + (wave*16 + l16)*AGSTRIDE + ks*32 + quad*8;
            floatx4 a0 = *(const floatx4*)ap;
            floatx4 a1 = *(const floatx4*)(ap + 4);
            #pragma unroll
            for (int i = 0; i < 4; ++i) {
                bfpair q0 = split1(a0[i]); ah[i]   = q0.h; al[i]   = q0.l;
                bfpair q1 = split1(a1[i]); ah[4+i] = q1.h; al[4+i] = q1.l;
            }
        }
        #pragma unroll
        for (int ot = 0; ot < 4; ++ot) {
            bf16x8 th  = *(const bf16x8*)(Th + (size_t)(ot*16 + l16)*64 + ks*32 + quad*8);
            bf16x8 tlw = *(const bf16x8*)(Tl + (size_t)(ot*16 + l16)*64 + ks*32 + quad*8);
            oacc[ot] = MFMA(ah, th, oacc[ot]);
            oacc[ot] = MFMA(al, th, oacc[ot]);
            oacc[ot] = MFMA(ah, tlw, oacc[ot]);
        }
    }

    float* obase = out + (size_t)bb * (NNODE * XROW) + tt * ND;
    #pragma unroll
    for (int ot = 0; ot < 4; ++ot)
        #pragma unroll
        for (int r = 0; r < 4; ++r) {
            float v = oacc[ot][r];
            obase[(size_t)(row0 + wave*16 + quad*4 + r) * XROW + ot*16 + l16]
                = v > 0.f ? v : 0.f;
        }
}

// ---------------------------------------------------------------------------
// Fallback: verified R5 kernel (used only if workspace is too small).
// ---------------------------------------------------------------------------
__global__ void __launch_bounds__(256, 2)
spattn_fb(const float* __restrict__ x, const float* __restrict__ adj,
          const float* __restrict__ theta, float* __restrict__ out)
{
    __shared__ __align__(16) char smem[SMEM_FB];
    __bf16* Khi = (__bf16*)(smem + OFF_KHI);
    __bf16* Klo = (__bf16*)(smem + OFF_KLO);
    __bf16* Vhi = (__bf16*)(smem + OFF_VHI);
    __bf16* Vlo = (__bf16*)(smem + OFF_VLO);
    float*  Pm  = (float*)(smem + OFF_P);

    const int tid  = threadIdx.x;
    const int wave = tid >> 6;
    const int lane = tid & 63;
    const int l16  = lane & 15;
    const int quad = lane >> 4;

    const int bx   = blockIdx.x;
    const int g    = bx >> 3;
    const int rblk = bx & 7;
    const int bb   = g / NT;
    const int tt   = g - bb * NT;
    const int row0 = rblk * 128;

    const float* xbase = x + (size_t)bb * (NNODE * XROW) + tt * ND;

    bf16x8 qhi[2][2], qlo[2][2];
    #pragma unroll
    for (int mt = 0; mt < 2; ++mt) {
        const float* qsrc = xbase + (size_t)(row0 + wave*32 + mt*16 + l16) * XROW;
        #pragma unroll
        for (int ks = 0; ks < 2; ++ks) {
            floatx4 f0 = *(const floatx4*)(qsrc + ks*32 + quad*8);
            floatx4 f1 = *(const floatx4*)(qsrc + ks*32 + quad*8 + 4);
            #pragma unroll
            for (int i = 0; i < 4; ++i) {
                bfpair p0 = split1(f0[i]*QSCALE);
                qhi[mt][ks][i]   = p0.h; qlo[mt][ks][i]   = p0.l;
                bfpair p1 = split1(f1[i]*QSCALE);
                qhi[mt][ks][4+i] = p1.h; qlo[mt][ks][4+i] = p1.l;
            }
        }
    }

    const floatx4 vzero = {0.f, 0.f, 0.f, 0.f};
    floatx4 acc[2][4];
    #pragma unroll
    for (int mt = 0; mt < 2; ++mt)
        #pragma unroll
        for (int dt = 0; dt < 4; ++dt)
            acc[mt][dt] = vzero;
    float lpart[2][4] = {{0.f,0.f,0.f,0.f},{0.f,0.f,0.f,0.f}};

    const int skey = tid >> 3;
    const int sd0  = (tid & 7) * 8;
    const int svd  = tid >> 2;
    const int svk0 = (tid & 3) * 8;
    floatx4 kf0, kf1;
    float vf[8];

    {
        const float* ksrc = xbase + (size_t)skey * XROW + sd0;
        kf0 = *(const floatx4*)ksrc;
        kf1 = *(const floatx4*)(ksrc + 4);
        const float* vsrc = xbase + (size_t)svk0 * XROW + svd;
        #pragma unroll
        for (int i = 0; i < 8; ++i) vf[i] = vsrc[i * XROW];
    }

    for (int ct = 0; ct < 32; ++ct) {
        const int key0 = ct * 32;
        __syncthreads();
        {
            bf16x8 h, l;
            #pragma unroll
            for (int i = 0; i < 4; ++i) {
                bfpair p0 = split1(kf0[i]); h[i]   = p0.h; l[i]   = p0.l;
                bfpair p1 = split1(kf1[i]); h[4+i] = p1.h; l[4+i] = p1.l;
            }
            *(bf16x8*)(Khi + skey*KSTRIDE + sd0) = h;
            *(bf16x8*)(Klo + skey*KSTRIDE + sd0) = l;
            bf16x8 vh, vl;
            #pragma unroll
            for (int i = 0; i < 8; ++i) {
                bfpair p = split1(vf[i]); vh[i] = p.h; vl[i] = p.l;
            }
            *(bf16x8*)(Vhi + svd*VSTRIDE + svk0) = vh;
            *(bf16x8*)(Vlo + svd*VSTRIDE + svk0) = vl;
        }
        __syncthreads();
        if (ct < 31) {
            const int nk = key0 + 32;
            const float* ksrc = xbase + (size_t)(nk + skey) * XROW + sd0;
            kf0 = *(const floatx4*)ksrc;
            kf1 = *(const floatx4*)(ksrc + 4);
            const float* vsrc = xbase + (size_t)(nk + svk0) * XROW + svd;
            #pragma unroll
            for (int i = 0; i < 8; ++i) vf[i] = vsrc[i * XROW];
        }
        float av[2][2][4];
        #pragma unroll
        for (int mt = 0; mt < 2; ++mt)
            #pragma unroll
            for (int nt = 0; nt < 2; ++nt)
                #pragma unroll
                for (int r = 0; r < 4; ++r)
                    av[mt][nt][r] = adj[(size_t)(row0 + wave*32 + mt*16 + quad*4 + r) * NNODE
                                        + key0 + nt*16 + l16];

        floatx4 S[2][2] = {{vzero, vzero}, {vzero, vzero}};
        #pragma unroll
        for (int ks = 0; ks < 2; ++ks) {
            #pragma unroll
            for (int nt = 0; nt < 2; ++nt) {
                bf16x8 bh = *(const bf16x8*)(Khi + (nt*16 + l16)*KSTRIDE + ks*32 + quad*8);
                bf16x8 bl = *(const bf16x8*)(Klo + (nt*16 + l16)*KSTRIDE + ks*32 + quad*8);
                #pragma unroll
                for (int mt = 0; mt < 2; ++mt) {
                    S[mt][nt] = MFMA(qhi[mt][ks], bh, S[mt][nt]);
                    S[mt][nt] = MFMA(qlo[mt][ks], bh, S[mt][nt]);
                    S[mt][nt] = MFMA(qhi[mt][ks], bl, S[mt][nt]);
                }
            }
        }
        #pragma unroll
        for (int mt = 0; mt < 2; ++mt)
            #pragma unroll
            for (int nt = 0; nt < 2; ++nt)
                #pragma unroll
                for (int r = 0; r < 4; ++r) {
                    float w = __builtin_amdgcn_exp2f(S[mt][nt][r]);
                    lpart[mt][r] += w;
                    Pm[(wave*32 + mt*16 + quad*4 + r)*PSTRIDE + nt*16 + l16] = av[mt][nt][r] * w;
                }
        bf16x8 pah[2], pal[2];
        #pragma unroll
        for (int mt = 0; mt < 2; ++mt) {
            const float* pp = Pm + (wave*32 + mt*16 + l16)*PSTRIDE + quad*8;
            floatx4 p0 = *(const floatx4*)pp;
            floatx4 p1 = *(const floatx4*)(pp + 4);
            #pragma unroll
            for (int i = 0; i < 4; ++i) {
                bfpair q0 = split1(p0[i]); pah[mt][i]   = q0.h; pal[mt][i]   = q0.l;
                bfpair q1 = split1(p1[i]); pah[mt][4+i] = q1.h; pal[mt][4+i] = q1.l;
            }
        }
        #pragma unroll
        for (int dt = 0; dt < 4; ++dt) {
            bf16x8 vh = *(const bf16x8*)(Vhi + (dt*16 + l16)*VSTRIDE + quad*8);
            bf16x8 vl = *(const bf16x8*)(Vlo + (dt*16 + l16)*VSTRIDE + quad*8);
            #pragma unroll
            for (int mt = 0; mt < 2; ++mt) {
                acc[mt][dt] = MFMA(pah[mt], vh, acc[mt][dt]);
                acc[mt][dt] = MFMA(pal[mt], vh, acc[mt][dt]);
                acc[mt][dt] = MFMA(pah[mt], vl, acc[mt][dt]);
            }
        }
    }

    float linv[2][4];
    #pragma unroll
    for (int mt = 0; mt < 2; ++mt)
        #pragma unroll
        for (int r = 0; r < 4; ++r) {
            float lv = lpart[mt][r];
            lv += __shfl_xor(lv, 1);
            lv += __shfl_xor(lv, 2);
            lv += __shfl_xor(lv, 4);
            lv += __shfl_xor(lv, 8);
            linv[mt][r] = 1.0f / lv;
        }

    __syncthreads();
    float* AG = (float*)smem;
    #pragma unroll
    for (int mt = 0; mt < 2; ++mt)
        #pragma unroll
        for (int dt = 0; dt < 4; ++dt)
            #pragma unroll
            for (int r = 0; r < 4; ++r)
                AG[(wave*32 + mt*16 + quad*4 + r)*AGSTRIDE + dt*16 + l16]
                    = acc[mt][dt][r] * linv[mt][r];

    bf16x8 th[4][2], tl[4][2];
    #pragma unroll
    for (int ot = 0; ot < 4; ++ot)
        #pragma unroll
        for (int ks = 0; ks < 2; ++ks)
            #pragma unroll
            for (int j = 0; j < 8; ++j) {
                float tv = theta[(ks*32 + quad*8 + j)*ND + ot*16 + l16];
                bfpair p = split1(tv);
                th[ot][ks][j] = p.h; tl[ot][ks][j] = p.l;
            }

    floatx4 oacc[2][4];
    #pragma unroll
    for (int mt = 0; mt < 2; ++mt)
        #pragma unroll
        for (int ot = 0; ot < 4; ++ot)
            oacc[mt][ot] = vzero;
    __syncthreads();
    #pragma unroll
    for (int ks = 0; ks < 2; ++ks) {
        bf16x8 ah[2], al[2];
        #pragma unroll
        for (int mt = 0; mt < 2; ++mt) {
            const float* ap = AG + (wave*32 + mt*16 + l16)*AGSTRIDE + ks*32 + quad*8;
            floatx4 a0 = *(const floatx4*)ap;
            floatx4 a1 = *(const floatx4*)(ap + 4);
            #pragma unroll
            for (int i = 0; i < 4; ++i) {
                bfpair q0 = split1(a0[i]); ah[mt][i]   = q0.h; al[mt][i]   = q0.l;
                bfpair q1 = split1(a1[i]); ah[mt][4+i] = q1.h; al[mt][4+i] = q1.l;
            }
        }
        #pragma unroll
        for (int ot = 0; ot < 4; ++ot)
            #pragma unroll
            for (int mt = 0; mt < 2; ++mt) {
                oacc[mt][ot] = MFMA(ah[mt], th[ot][ks], oacc[mt][ot]);
                oacc[mt][ot] = MFMA(al[mt], th[ot][ks], oacc[mt][ot]);
                oacc[mt][ot] = MFMA(ah[mt], tl[ot][ks], oacc[mt][ot]);
            }
    }

    float* obase = out + (size_t)bb * (NNODE * XROW) + tt * ND;
    #pragma unroll
    for (int mt = 0; mt < 2; ++mt)
        #pragma unroll
        for (int ot = 0; ot < 4; ++ot)
            #pragma unroll
            for (int r = 0; r < 4; ++r) {
                float v = oacc[mt][ot][r];
                obase[(size_t)(row0 + wave*32 + mt*16 + quad*4 + r) * XROW + ot*16 + l16]
                    = v > 0.f ? v : 0.f;
            }
}

extern "C" void kernel_launch(void* const* d_in, const int* in_sizes, int n_in,
                              void* d_out, int out_size, void* d_ws, size_t ws_size,
                              hipStream_t stream) {
    (void)in_sizes; (void)n_in; (void)out_size;
    const float* x     = (const float*)d_in[0];
    const float* adj   = (const float*)d_in[1];
    const float* theta = (const float*)d_in[2];
    float* out = (float*)d_out;
    if (d_ws != nullptr && ws_size >= WS_BYTES) {
        __bf16* ws = (__bf16*)d_ws;
        presplit<<<dim3(1536), dim3(256), 0, stream>>>(x, theta, ws);
        spattn7<<<dim3(1536), dim3(256), 0, stream>>>(ws, adj, out);
    } else {
        spattn_fb<<<dim3(768), dim3(256), 0, stream>>>(x, adj, theta, out);
    }
}

// Round 8
// 167.487 us; speedup vs baseline: 1.3801x; 1.0984x over previous
//
#include <hip/hip_runtime.h>

// PositionWiseSpatialAttention — fused flash-style kernel, MI355X gfx950.
//
// R13 = R10 engine (128-row blocks, swapped QK^T, register P, permuted-V ws)
// plus two structural cuts:
//  (1) theta folded into V at presplit: W = X·Θ computed per 64-row tile with
//      split-bf16 MFMA (same 3-term scheme the old epilogue used), stored in
//      the VERIFIED permuted-transposed layout. Main kernel computes P·W and
//      the whole epilogue (AG LDS round-trip + theta + 2 barriers) vanishes:
//      out = relu(acc * linv) stored directly.
//  (2) double-buffered K/W staging, ONE barrier per iteration (32 vs 66):
//      after the barrier, write tile ct+1 into the dead buffer, then compute
//      tile ct — kills the write->barrier->read serialization.
// Ledger: R12 proved occupancy is not the limit (28->58%, time worse) and
// 64-row blocks saturate the LDS pipe; 128-row is the right reuse point.
// R11/R8 proved global-direct frag reads expose L2 latency. So: same LDS
// staging pattern, less of it, fewer barriers.

#define NB    8
#define NT    12
#define NNODE 1024
#define ND    64
#define XROW  768   /* NT*ND: stride between consecutive n for fixed (b,t) */
#define NG    96    /* NB*NT */

typedef __bf16 bf16x8 __attribute__((ext_vector_type(8)));
typedef __bf16 bf16x4 __attribute__((ext_vector_type(4)));
typedef float  floatx4 __attribute__((ext_vector_type(4)));

#define MFMA(a,b,c) __builtin_amdgcn_mfma_f32_16x16x32_bf16((a),(b),(c),0,0,0)

#define QSCALE 0.18033688011112042f   /* 0.125 * log2(e) */

// Per-buffer LDS layout (bytes); two buffers for the main kernel.
#define KSTRIDE 72   /* bf16 per K row: 144 B */
#define VSTRIDE 40   /* bf16 per W row:  80 B */
#define OFF_KHI 0
#define OFF_KLO 4608
#define OFF_WHI 9216
#define OFF_WLO 14336
#define BUFSZ   19456
#define SMEM8   (2 * BUFSZ)               /* 38912 */
// fallback (R5) LDS map
#define PSTRIDE 36
#define AGSTRIDE 68
#define OFF_VHI 9216
#define OFF_VLO 14336
#define OFF_P   19456
#define SMEM_FB (19456 + 128*PSTRIDE*4)   /* 37888 */

// workspace element offsets (__bf16 units)
#define WXHI  0          /* [96][1024][64] row-major hi           */
#define WXLO  6291456
#define WVPHI 12582912   /* [96][64 o][1024] W^T permuted hi       */
#define WVPLO 18874368
#define WS_BYTES 50348032ULL

struct bfpair { __bf16 h, l; };

// error-compensated split: hi = RNE(f) via native fptrunc, lo = RNE(f - hi).
__device__ __forceinline__ bfpair split1(float f) {
    bfpair r;
    __bf16 hb = (__bf16)f;
    float hf = __builtin_bit_cast(float,
                   (unsigned)__builtin_bit_cast(unsigned short, hb) << 16);
    r.h = hb;
    r.l = (__bf16)(f - hf);
    return r;
}

// ---------------------------------------------------------------------------
// presplit: grid 1536 (96 g x 16 n-blocks), 256 threads.
// Phase A (verified): x tile -> T (LDS) + row-major split -> Xhi/Xlo.
// Phase B (new): W = T · Θ via 3-term split-bf16 MFMA (the old epilogue's
//   exact scheme), result -> Wt (LDS, f32, [key][o]).
// Phase C (verified code path): transposed+PERMUTED split of Wt -> WVPhi/lo.
//   Position c in each 32-key tile holds key k(c)=((c&7)>>2)*16+(c>>3)*4+(c&3).
// ---------------------------------------------------------------------------
__global__ void __launch_bounds__(256)
presplit(const float* __restrict__ x, const float* __restrict__ theta,
         __bf16* __restrict__ ws)
{
    __shared__ __align__(16) float T[64 * 68];
    __shared__ __align__(16) float Wt[64 * 68];
    const int tid  = threadIdx.x;
    const int lane = tid & 63;
    const int wave = tid >> 6;
    const int l16  = lane & 15;
    const int quad = lane >> 4;
    const int bx   = blockIdx.x;
    const int g    = bx >> 4;
    const int nblk = bx & 15;
    const int bb   = g / NT;
    const int tt   = g - bb * NT;
    const int n0   = nblk * 64;

    __bf16* Xhi  = ws + WXHI  + (size_t)g * 65536;
    __bf16* Xlo  = ws + WXLO  + (size_t)g * 65536;
    __bf16* WPhi = ws + WVPHI + (size_t)g * 65536;
    __bf16* WPlo = ws + WVPLO + (size_t)g * 65536;
    const float* xg = x + (size_t)bb * (NNODE * XROW) + (size_t)tt * ND;

    // ---- Phase A: 64x64 fp32 tile -> T + row-major split ----
    #pragma unroll
    for (int i = 0; i < 4; ++i) {
        int chunk = i * 256 + tid;        // 0..1023
        int n  = chunk >> 4;              // 0..63
        int c4 = (chunk & 15) * 4;        // 0..60
        floatx4 f = *(const floatx4*)(xg + (size_t)(n0 + n) * XROW + c4);
        *(floatx4*)(T + n * 68 + c4) = f;
        bf16x4 h, l;
        #pragma unroll
        for (int j = 0; j < 4; ++j) {
            bfpair p = split1(f[j]); h[j] = p.h; l[j] = p.l;
        }
        *(bf16x4*)(Xhi + (size_t)(n0 + n) * 64 + c4) = h;
        *(bf16x4*)(Xlo + (size_t)(n0 + n) * 64 + c4) = l;
    }
    __syncthreads();

    // ---- Phase B: W = T · Θ (3-term split-bf16 MFMA), wave owns 16 keys ----
    {
        // A-frags from T: row = wave*16 + l16, elem = ks*32 + quad*8 + j
        bf16x8 tah[2], tal[2];
        #pragma unroll
        for (int ks = 0; ks < 2; ++ks)
            #pragma unroll
            for (int j = 0; j < 8; ++j) {
                bfpair p = split1(T[(wave*16 + l16)*68 + ks*32 + quad*8 + j]);
                tah[ks][j] = p.h; tal[ks][j] = p.l;
            }
        const floatx4 vz = {0.f, 0.f, 0.f, 0.f};
        #pragma unroll
        for (int ot = 0; ot < 4; ++ot) {
            // B-frags from theta^T: row o = ot*16 + l16, elem = ks*32+quad*8+j
            bf16x8 thb[2], tlb[2];
            #pragma unroll
            for (int ks = 0; ks < 2; ++ks)
                #pragma unroll
                for (int j = 0; j < 8; ++j) {
                    bfpair p = split1(theta[(size_t)(ks*32 + quad*8 + j) * ND
                                            + ot*16 + l16]);
                    thb[ks][j] = p.h; tlb[ks][j] = p.l;
                }
            floatx4 Wc = vz;
            #pragma unroll
            for (int ks = 0; ks < 2; ++ks) {
                Wc = MFMA(tah[ks], thb[ks], Wc);
                Wc = MFMA(tal[ks], thb[ks], Wc);
                Wc = MFMA(tah[ks], tlb[ks], Wc);
            }
            // lane holds W[key = wave*16 + quad*4 + r][o = ot*16 + l16]
            #pragma unroll
            for (int r = 0; r < 4; ++r)
                Wt[(wave*16 + quad*4 + r)*68 + ot*16 + l16] = Wc[r];
        }
    }
    __syncthreads();

    // ---- Phase C: transposed + permuted split of Wt (verified code) ----
    {
        const int o  = tid >> 2;          // 0..63
        const int nc = (tid & 3) * 16;    // 0..48 (dst positions nc..nc+15)
        const int tb = nc & 32;           // 32-key tile base within the 64-blk
        bf16x8 h0, l0, h1, l1;
        #pragma unroll
        for (int j = 0; j < 8; ++j) {
            int c0 = (nc & 31) + j;       // dst position in tile
            int k0 = ((c0 & 7) >> 2) * 16 + (c0 >> 3) * 4 + (c0 & 3);
            bfpair p = split1(Wt[(tb + k0) * 68 + o]);
            h0[j] = p.h; l0[j] = p.l;
            int c1 = (nc & 31) + 8 + j;
            int k1 = ((c1 & 7) >> 2) * 16 + (c1 >> 3) * 4 + (c1 & 3);
            bfpair q = split1(Wt[(tb + k1) * 68 + o]);
            h1[j] = q.h; l1[j] = q.l;
        }
        __bf16* dsth = WPhi + (size_t)o * NNODE + n0 + nc;
        __bf16* dstl = WPlo + (size_t)o * NNODE + n0 + nc;
        *(bf16x8*)dsth = h0; *(bf16x8*)(dsth + 8) = h1;
        *(bf16x8*)dstl = l0; *(bf16x8*)(dstl + 8) = l1;
    }
}

// ---------------------------------------------------------------------------
// spattn8: grid 768 (bx = rblk*96 + g), 256 threads, 4 waves x 32 rows.
// Swapped QK^T, register P, double-buffered K/W staging, 1 barrier/iter,
// no epilogue (theta pre-folded into W).
// ---------------------------------------------------------------------------
__global__ void __launch_bounds__(256, 3)
spattn8(const __bf16* __restrict__ ws, const float* __restrict__ adj,
        float* __restrict__ out)
{
    __shared__ __align__(16) char smem[SMEM8];

    const int tid  = threadIdx.x;
    const int wave = tid >> 6;          // 0..3, owns rows wave*32..+31
    const int lane = tid & 63;
    const int l16  = lane & 15;
    const int quad = lane >> 4;

    // bx = rblk*96 + g: all 8 row-blocks of a g share bx%8 -> same XCD.
    const int bx   = blockIdx.x;
    const int g    = bx % NG;           // 0..95
    const int rblk = bx / NG;           // 0..7
    const int bb   = g / NT;
    const int tt   = g - bb * NT;
    const int row0 = rblk * 128;

    const __bf16* xh  = ws + WXHI  + (size_t)g * 65536;
    const __bf16* xl  = ws + WXLO  + (size_t)g * 65536;
    const __bf16* wph = ws + WVPHI + (size_t)g * 65536;
    const __bf16* wpl = ws + WVPLO + (size_t)g * 65536;

    // ---- Q fragments b128 from row-major split arrays (B operand) ----
    bf16x8 qhi[2][2], qlo[2][2];
    #pragma unroll
    for (int mt = 0; mt < 2; ++mt) {
        const __bf16* q0 = xh + (size_t)(row0 + wave*32 + mt*16 + l16) * 64 + quad*8;
        const __bf16* q1 = xl + (size_t)(row0 + wave*32 + mt*16 + l16) * 64 + quad*8;
        #pragma unroll
        for (int ks = 0; ks < 2; ++ks) {
            qhi[mt][ks] = *(const bf16x8*)(q0 + ks*32);
            qlo[mt][ks] = *(const bf16x8*)(q1 + ks*32);
        }
    }

    const floatx4 vzero = {0.f, 0.f, 0.f, 0.f};
    floatx4 acc[2][4];
    #pragma unroll
    for (int mt = 0; mt < 2; ++mt)
        #pragma unroll
        for (int dt = 0; dt < 4; ++dt)
            acc[mt][dt] = vzero;
    float lpart[2] = {0.f, 0.f};        // per-lane partial: q = l16 (per mt)

    // staging maps (verified geometry)
    const int skey = tid >> 3;          // 0..31
    const int sd0  = (tid & 7) * 8;     // 0..56
    const int svd  = tid >> 2;          // 0..63 (o-row of W^T)
    const int svk0 = (tid & 3) * 8;     // 0..24

    // prologue: stage tile 0 into buffer 0, prefetch tile 1 into regs
    bf16x8 kh, kl, wh, wl;
    kh = *(const bf16x8*)(xh  + (size_t)skey * 64 + sd0);
    kl = *(const bf16x8*)(xl  + (size_t)skey * 64 + sd0);
    wh = *(const bf16x8*)(wph + (size_t)svd * NNODE + svk0);
    wl = *(const bf16x8*)(wpl + (size_t)svd * NNODE + svk0);
    {
        char* b0 = smem;
        *(bf16x8*)((__bf16*)(b0 + OFF_KHI) + skey*KSTRIDE + sd0) = kh;
        *(bf16x8*)((__bf16*)(b0 + OFF_KLO) + skey*KSTRIDE + sd0) = kl;
        *(bf16x8*)((__bf16*)(b0 + OFF_WHI) + svd*VSTRIDE + svk0) = wh;
        *(bf16x8*)((__bf16*)(b0 + OFF_WLO) + svd*VSTRIDE + svk0) = wl;
    }
    kh = *(const bf16x8*)(xh  + (size_t)(32 + skey) * 64 + sd0);
    kl = *(const bf16x8*)(xl  + (size_t)(32 + skey) * 64 + sd0);
    wh = *(const bf16x8*)(wph + (size_t)svd * NNODE + 32 + svk0);
    wl = *(const bf16x8*)(wpl + (size_t)svd * NNODE + 32 + svk0);

    int cur = 0;
    for (int ct = 0; ct < 32; ++ct) {
        const int key0 = ct * 32;
        __syncthreads();   // all waves done reading buf[cur^1] (tile ct-1);
                           // buf[cur] (tile ct) writes now visible
        if (ct < 31) {     // write tile ct+1 into the dead buffer
            char* wb = smem + (cur ^ 1) * BUFSZ;
            *(bf16x8*)((__bf16*)(wb + OFF_KHI) + skey*KSTRIDE + sd0) = kh;
            *(bf16x8*)((__bf16*)(wb + OFF_KLO) + skey*KSTRIDE + sd0) = kl;
            *(bf16x8*)((__bf16*)(wb + OFF_WHI) + svd*VSTRIDE + svk0) = wh;
            *(bf16x8*)((__bf16*)(wb + OFF_WLO) + svd*VSTRIDE + svk0) = wl;
        }
        if (ct < 30) {     // prefetch tile ct+2 into regs (overlaps compute)
            const int nk = key0 + 64;
            kh = *(const bf16x8*)(xh  + (size_t)(nk + skey) * 64 + sd0);
            kl = *(const bf16x8*)(xl  + (size_t)(nk + skey) * 64 + sd0);
            wh = *(const bf16x8*)(wph + (size_t)svd * NNODE + nk + svk0);
            wl = *(const bf16x8*)(wpl + (size_t)svd * NNODE + nk + svk0);
        }
        // adj: float4 loads; lane l16 = q-row, quad*4+r = key within nt-tile
        floatx4 av[2][2];
        #pragma unroll
        for (int mt = 0; mt < 2; ++mt)
            #pragma unroll
            for (int nt = 0; nt < 2; ++nt)
                av[mt][nt] = *(const floatx4*)(adj
                    + (size_t)(row0 + wave*32 + mt*16 + l16) * NNODE
                    + key0 + nt*16 + quad*4);

        char* rb = smem + cur * BUFSZ;
        __bf16* Khi = (__bf16*)(rb + OFF_KHI);
        __bf16* Klo = (__bf16*)(rb + OFF_KLO);
        __bf16* Whi = (__bf16*)(rb + OFF_WHI);
        __bf16* Wlo = (__bf16*)(rb + OFF_WLO);

        // ---- S^T = K Q^T (swapped operands; 3-term split bf16) ----
        // Output: col = q = l16, row = key = nt*16 + quad*4 + r.
        floatx4 S[2][2] = {{vzero, vzero}, {vzero, vzero}};   // [mt][nt]
        #pragma unroll
        for (int ks = 0; ks < 2; ++ks) {
            #pragma unroll
            for (int nt = 0; nt < 2; ++nt) {
                bf16x8 ah = *(const bf16x8*)(Khi + (nt*16 + l16)*KSTRIDE + ks*32 + quad*8);
                bf16x8 al = *(const bf16x8*)(Klo + (nt*16 + l16)*KSTRIDE + ks*32 + quad*8);
                #pragma unroll
                for (int mt = 0; mt < 2; ++mt) {
                    S[mt][nt] = MFMA(ah, qhi[mt][ks], S[mt][nt]);
                    S[mt][nt] = MFMA(ah, qlo[mt][ks], S[mt][nt]);
                    S[mt][nt] = MFMA(al, qhi[mt][ks], S[mt][nt]);
                }
            }
        }

        // ---- exp2 + adj-mask + split, ALL in registers ----
        bf16x8 pah[2], pal[2];
        #pragma unroll
        for (int mt = 0; mt < 2; ++mt)
            #pragma unroll
            for (int nt = 0; nt < 2; ++nt)
                #pragma unroll
                for (int r = 0; r < 4; ++r) {
                    float w = __builtin_amdgcn_exp2f(S[mt][nt][r] * QSCALE);
                    lpart[mt] += w;
                    bfpair pp = split1(av[mt][nt][r] * w);
                    pah[mt][nt*4 + r] = pp.h;
                    pal[mt][nt*4 + r] = pp.l;
                }

        // ---- acc += P . W (3-term split; W B-frags from permuted LDS) ----
        #pragma unroll
        for (int dt = 0; dt < 4; ++dt) {
            bf16x8 wvh = *(const bf16x8*)(Whi + (dt*16 + l16)*VSTRIDE + quad*8);
            bf16x8 wvl = *(const bf16x8*)(Wlo + (dt*16 + l16)*VSTRIDE + quad*8);
            #pragma unroll
            for (int mt = 0; mt < 2; ++mt) {
                acc[mt][dt] = MFMA(pah[mt], wvh, acc[mt][dt]);
                acc[mt][dt] = MFMA(pal[mt], wvh, acc[mt][dt]);
                acc[mt][dt] = MFMA(pah[mt], wvl, acc[mt][dt]);
            }
        }
        cur ^= 1;
    }

    // ---- denominator: reduce across quads (each lane has q = l16) ----
    float linv[2][4];
    #pragma unroll
    for (int mt = 0; mt < 2; ++mt) {
        float lv = lpart[mt];
        lv += __shfl_xor(lv, 16);
        lv += __shfl_xor(lv, 32);           // every lane: full sum for q=l16
        #pragma unroll
        for (int r = 0; r < 4; ++r)
            linv[mt][r] = 1.0f / __shfl(lv, quad*4 + r);
    }

    // ---- store: out = relu(acc * linv) — no epilogue matmul needed ----
    float* obase = out + (size_t)bb * (NNODE * XROW) + tt * ND;
    #pragma unroll
    for (int mt = 0; mt < 2; ++mt)
        #pragma unroll
        for (int dt = 0; dt < 4; ++dt)
            #pragma unroll
            for (int r = 0; r < 4; ++r) {
                float v = acc[mt][dt][r] * linv[mt][r];
                obase[(size_t)(row0 + wave*32 + mt*16 + quad*4 + r) * XROW + dt*16 + l16]
                    = v > 0.f ? v : 0.f;
            }
}

// ---------------------------------------------------------------------------
// Fallback: verified R5 kernel (used only if workspace is too small).
// ---------------------------------------------------------------------------
__global__ void __launch_bounds__(256, 2)
spattn_fb(const float* __restrict__ x, const float* __restrict__ adj,
          const float* __restrict__ theta, float* __restrict__ out)
{
    __shared__ __align__(16) char smem[SMEM_FB];
    __bf16* Khi = (__bf16*)(smem + OFF_KHI);
    __bf16* Klo = (__bf16*)(smem + OFF_KLO);
    __bf16* Vhi = (__bf16*)(smem + OFF_VHI);
    __bf16* Vlo = (__bf16*)(smem + OFF_VLO);
    float*  Pm  = (float*)(smem + OFF_P);

    const int tid  = threadIdx.x;
    const int wave = tid >> 6;
    const int lane = tid & 63;
    const int l16  = lane & 15;
    const int quad = lane >> 4;

    const int bx   = blockIdx.x;
    const int g    = bx >> 3;
    const int rblk = bx & 7;
    const int bb   = g / NT;
    const int tt   = g - bb * NT;
    const int row0 = rblk * 128;

    const float* xbase = x + (size_t)bb * (NNODE * XROW) + tt * ND;

    bf16x8 qhi[2][2], qlo[2][2];
    #pragma unroll
    for (int mt = 0; mt < 2; ++mt) {
        const float* qsrc = xbase + (size_t)(row0 + wave*32 + mt*16 + l16) * XROW;
        #pragma unroll
        for (int ks = 0; ks < 2; ++ks) {
            floatx4 f0 = *(const floatx4*)(qsrc + ks*32 + quad*8);
            floatx4 f1 = *(const floatx4*)(qsrc + ks*32 + quad*8 + 4);
            #pragma unroll
            for (int i = 0; i < 4; ++i) {
                bfpair p0 = split1(f0[i]*QSCALE);
                qhi[mt][ks][i]   = p0.h; qlo[mt][ks][i]   = p0.l;
                bfpair p1 = split1(f1[i]*QSCALE);
                qhi[mt][ks][4+i] = p1.h; qlo[mt][ks][4+i] = p1.l;
            }
        }
    }

    const floatx4 vzero = {0.f, 0.f, 0.f, 0.f};
    floatx4 acc[2][4];
    #pragma unroll
    for (int mt = 0; mt < 2; ++mt)
        #pragma unroll
        for (int dt = 0; dt < 4; ++dt)
            acc[mt][dt] = vzero;
    float lpart[2][4] = {{0.f,0.f,0.f,0.f},{0.f,0.f,0.f,0.f}};

    const int skey = tid >> 3;
    const int sd0  = (tid & 7) * 8;
    const int svd  = tid >> 2;
    const int svk0 = (tid & 3) * 8;
    floatx4 kf0, kf1;
    float vf[8];

    {
        const float* ksrc = xbase + (size_t)skey * XROW + sd0;
        kf0 = *(const floatx4*)ksrc;
        kf1 = *(const floatx4*)(ksrc + 4);
        const float* vsrc = xbase + (size_t)svk0 * XROW + svd;
        #pragma unroll
        for (int i = 0; i < 8; ++i) vf[i] = vsrc[i * XROW];
    }

    for (int ct = 0; ct < 32; ++ct) {
        const int key0 = ct * 32;
        __syncthreads();
        {
            bf16x8 h, l;
            #pragma unroll
            for (int i = 0; i < 4; ++i) {
                bfpair p0 = split1(kf0[i]); h[i]   = p0.h; l[i]   = p0.l;
                bfpair p1 = split1(kf1[i]); h[4+i] = p1.h; l[4+i] = p1.l;
            }
            *(bf16x8*)(Khi + skey*KSTRIDE + sd0) = h;
            *(bf16x8*)(Klo + skey*KSTRIDE + sd0) = l;
            bf16x8 vh, vl;
            #pragma unroll
            for (int i = 0; i < 8; ++i) {
                bfpair p = split1(vf[i]); vh[i] = p.h; vl[i] = p.l;
            }
            *(bf16x8*)(Vhi + svd*VSTRIDE + svk0) = vh;
            *(bf16x8*)(Vlo + svd*VSTRIDE + svk0) = vl;
        }
        __syncthreads();
        if (ct < 31) {
            const int nk = key0 + 32;
            const float* ksrc = xbase + (size_t)(nk + skey) * XROW + sd0;
            kf0 = *(const floatx4*)ksrc;
            kf1 = *(const floatx4*)(ksrc + 4);
            const float* vsrc = xbase + (size_t)(nk + svk0) * XROW + svd;
            #pragma unroll
            for (int i = 0; i < 8; ++i) vf[i] = vsrc[i * XROW];
        }
        float av[2][2][4];
        #pragma unroll
        for (int mt = 0; mt < 2; ++mt)
            #pragma unroll
            for (int nt = 0; nt < 2; ++nt)
                #pragma unroll
                for (int r = 0; r < 4; ++r)
                    av[mt][nt][r] = adj[(size_t)(row0 + wave*32 + mt*16 + quad*4 + r) * NNODE
                                        + key0 + nt*16 + l16];

        floatx4 S[2][2] = {{vzero, vzero}, {vzero, vzero}};
        #pragma unroll
        for (int ks = 0; ks < 2; ++ks) {
            #pragma unroll
            for (int nt = 0; nt < 2; ++nt) {
                bf16x8 bh = *(const bf16x8*)(Khi + (nt*16 + l16)*KSTRIDE + ks*32 + quad*8);
                bf16x8 bl = *(const bf16x8*)(Klo + (nt*16 + l16)*KSTRIDE + ks*32 + quad*8);
                #pragma unroll
                for (int mt = 0; mt < 2; ++mt) {
                    S[mt][nt] = MFMA(qhi[mt][ks], bh, S[mt][nt]);
                    S[mt][nt] = MFMA(qlo[mt][ks], bh, S[mt][nt]);
                    S[mt][nt] = MFMA(qhi[mt][ks], bl, S[mt][nt]);
                }
            }
        }
        #pragma unroll
        for (int mt = 0; mt < 2; ++mt)
            #pragma unroll
            for (int nt = 0; nt < 2; ++nt)
                #pragma unroll
                for (int r = 0; r < 4; ++r) {
                    float w = __builtin_amdgcn_exp2f(S[mt][nt][r]);
                    lpart[mt][r] += w;
                    Pm[(wave*32 + mt*16 + quad*4 + r)*PSTRIDE + nt*16 + l16] = av[mt][nt][r] * w;
                }
        bf16x8 pah[2], pal[2];
        #pragma unroll
        for (int mt = 0; mt < 2; ++mt) {
            const float* pp = Pm + (wave*32 + mt*16 + l16)*PSTRIDE + quad*8;
            floatx4 p0 = *(const floatx4*)pp;
            floatx4 p1 = *(const floatx4*)(pp + 4);
            #pragma unroll
            for (int i = 0; i < 4; ++i) {
                bfpair q0 = split1(p0[i]); pah[mt][i]   = q0.h; pal[mt][i]   = q0.l;
                bfpair q1 = split1(p1[i]); pah[mt][4+i] = q1.h; pal[mt][4+i] = q1.l;
            }
        }
        #pragma unroll
        for (int dt = 0; dt < 4; ++dt) {
            bf16x8 vh = *(const bf16x8*)(Vhi + (dt*16 + l16)*VSTRIDE + quad*8);
            bf16x8 vl = *(const bf16x8*)(Vlo + (dt*16 + l16)*VSTRIDE + quad*8);
            #pragma unroll
            for (int mt = 0; mt < 2; ++mt) {
                acc[mt][dt] = MFMA(pah[mt], vh, acc[mt][dt]);
                acc[mt][dt] = MFMA(pal[mt], vh, acc[mt][dt]);
                acc[mt][dt] = MFMA(pah[mt], vl, acc[mt][dt]);
            }
        }
    }

    float linv[2][4];
    #pragma unroll
    for (int mt = 0; mt < 2; ++mt)
        #pragma unroll
        for (int r = 0; r < 4; ++r) {
            float lv = lpart[mt][r];
            lv += __shfl_xor(lv, 1);
            lv += __shfl_xor(lv, 2);
            lv += __shfl_xor(lv, 4);
            lv += __shfl_xor(lv, 8);
            linv[mt][r] = 1.0f / lv;
        }

    __syncthreads();
    float* AG = (float*)smem;
    #pragma unroll
    for (int mt = 0; mt < 2; ++mt)
        #pragma unroll
        for (int dt = 0; dt < 4; ++dt)
            #pragma unroll
            for (int r = 0; r < 4; ++r)
                AG[(wave*32 + mt*16 + quad*4 + r)*AGSTRIDE + dt*16 + l16]
                    = acc[mt][dt][r] * linv[mt][r];

    bf16x8 th[4][2], tl[4][2];
    #pragma unroll
    for (int ot = 0; ot < 4; ++ot)
        #pragma unroll
        for (int ks = 0; ks < 2; ++ks)
            #pragma unroll
            for (int j = 0; j < 8; ++j) {
                float tv = theta[(ks*32 + quad*8 + j)*ND + ot*16 + l16];
                bfpair p = split1(tv);
                th[ot][ks][j] = p.h; tl[ot][ks][j] = p.l;
            }

    floatx4 oacc[2][4];
    #pragma unroll
    for (int mt = 0; mt < 2; ++mt)
        #pragma unroll
        for (int ot = 0; ot < 4; ++ot)
            oacc[mt][ot] = vzero;
    __syncthreads();
    #pragma unroll
    for (int ks = 0; ks < 2; ++ks) {
        bf16x8 ah[2], al[2];
        #pragma unroll
        for (int mt = 0; mt < 2; ++mt) {
            const float* ap = AG + (wave*32 + mt*16 + l16)*AGSTRIDE + ks*32 + quad*8;
            floatx4 a0 = *(const floatx4*)ap;
            floatx4 a1 = *(const floatx4*)(ap + 4);
            #pragma unroll
            for (int i = 0; i < 4; ++i) {
                bfpair q0 = split1(a0[i]); ah[mt][i]   = q0.h; al[mt][i]   = q0.l;
                bfpair q1 = split1(a1[i]); ah[mt][4+i] = q1.h; al[mt][4+i] = q1.l;
            }
        }
        #pragma unroll
        for (int ot = 0; ot < 4; ++ot)
            #pragma unroll
            for (int mt = 0; mt < 2; ++mt) {
                oacc[mt][ot] = MFMA(ah[mt], th[ot][ks], oacc[mt][ot]);
                oacc[mt][ot] = MFMA(al[mt], th[ot][ks], oacc[mt][ot]);
                oacc[mt][ot] = MFMA(ah[mt], tl[ot][ks], oacc[mt][ot]);
            }
    }

    float* obase = out + (size_t)bb * (NNODE * XROW) + tt * ND;
    #pragma unroll
    for (int mt = 0; mt < 2; ++mt)
        #pragma unroll
        for (int ot = 0; ot < 4; ++ot)
            #pragma unroll
            for (int r = 0; r < 4; ++r) {
                float v = oacc[mt][ot][r];
                obase[(size_t)(row0 + wave*32 + mt*16 + quad*4 + r) * XROW + ot*16 + l16]
                    = v > 0.f ? v : 0.f;
            }
}

extern "C" void kernel_launch(void* const* d_in, const int* in_sizes, int n_in,
                              void* d_out, int out_size, void* d_ws, size_t ws_size,
                              hipStream_t stream) {
    (void)in_sizes; (void)n_in; (void)out_size;
    const float* x     = (const float*)d_in[0];
    const float* adj   = (const float*)d_in[1];
    const float* theta = (const float*)d_in[2];
    float* out = (float*)d_out;
    if (d_ws != nullptr && ws_size >= WS_BYTES) {
        __bf16* ws = (__bf16*)d_ws;
        presplit<<<dim3(1536), dim3(256), 0, stream>>>(x, theta, ws);
        spattn8<<<dim3(768), dim3(256), 0, stream>>>(ws, adj, out);
    } else {
        spattn_fb<<<dim3(768), dim3(256), 0, stream>>>(x, adj, theta, out);
    }
}